// Round 1
// baseline (62.938 us; speedup 1.0000x reference)
//
#include <hip/hip_runtime.h>

#define B_  8
#define C_  256
#define H_  64
#define W_  64
#define G_  4
#define CG_ 64
#define K_  9
#define HW_ (H_ * W_)  // 4096

// ---------------------------------------------------------------------------
// Kernel 1: transpose NCHW -> NHWC ([B,C,H*W] -> [B,H*W,C]) via 32x32 LDS tile
// ---------------------------------------------------------------------------
__global__ __launch_bounds__(256) void nchw_to_nhwc(const float* __restrict__ in,
                                                    float* __restrict__ out) {
  __shared__ float tile[32][33];
  const int b  = blockIdx.z;
  const int p0 = blockIdx.x * 32;  // pixel tile
  const int c0 = blockIdx.y * 32;  // channel tile
  const float* src = in  + (size_t)b * C_ * HW_;
  float*       dst = out + (size_t)b * C_ * HW_;
  const int tx = threadIdx.x, ty = threadIdx.y;
#pragma unroll
  for (int i = 0; i < 32; i += 8)
    tile[ty + i][tx] = src[(size_t)(c0 + ty + i) * HW_ + p0 + tx];
  __syncthreads();
#pragma unroll
  for (int i = 0; i < 32; i += 8)
    dst[(size_t)(p0 + ty + i) * C_ + c0 + tx] = tile[tx][ty + i];
}

// ---------------------------------------------------------------------------
// Kernel 2: deformable sampling.
//   block = (b, g, ho, woq): 256 threads = 16 channel-quads x 16 wo pixels
//   phase 1: 144 threads compute per-(pixel,tap) corner offsets + pre-masked
//            bilinear weights into LDS (shared across 64 group channels)
//   phase 2: each thread accumulates 4 channels over 9 taps (float4 gathers
//            in NHWC mode), stages 64ch x 16wo tile in LDS, stores coalesced.
// ---------------------------------------------------------------------------
template <bool NHWC>
__global__ __launch_bounds__(256) void deform_main(const float* __restrict__ x,
                                                   const float* __restrict__ off,
                                                   const float* __restrict__ msk,
                                                   float* __restrict__ out) {
  __shared__ int4   s_o[144];
  __shared__ float4 s_w[144];
  __shared__ float  s_out[CG_ * 17];

  const int woq = blockIdx.x;        // 0..3  (wo chunk of 16)
  const int ho  = blockIdx.y;        // 0..63
  const int b   = blockIdx.z >> 2;   // 0..7
  const int g   = blockIdx.z & 3;    // 0..3
  const int tid = threadIdx.x;

  // ---- phase 1: sampling parameters for 16 pixels x 9 taps ----
  if (tid < 144) {
    const int wi = tid / 9, k = tid - wi * 9;
    const int wo = woq * 16 + wi;
    const int ky = k / 3, kx = k - ky * 3;
    const int och = (g * K_ + k) * 2;  // offset channel (dy); dx = +1 channel
    const size_t ob = ((size_t)(b * (2 * G_ * K_) + och) * H_ + ho) * W_ + wo;
    const float dy = off[ob];
    const float dx = off[ob + HW_];
    const float m  = msk[((size_t)(b * (G_ * K_) + g * K_ + k) * H_ + ho) * W_ + wo];

    const float py = (float)(ho - 1 + ky) + dy;
    const float px = (float)(wo - 1 + kx) + dx;
    const float fy = floorf(py), fx = floorf(px);
    const int y0 = (int)fy, x0 = (int)fx;
    const int y1 = y0 + 1,  x1 = x0 + 1;
    const float ly = py - fy, lx = px - fx;

    const bool vy0 = ((unsigned)y0 < (unsigned)H_), vy1 = ((unsigned)y1 < (unsigned)H_);
    const bool vx0 = ((unsigned)x0 < (unsigned)W_), vx1 = ((unsigned)x1 < (unsigned)W_);
    const float wy0 = (1.f - ly) * m, wy1 = ly * m;

    float4 w;
    w.x = (vy0 && vx0) ? wy0 * (1.f - lx) : 0.f;
    w.y = (vy0 && vx1) ? wy0 * lx         : 0.f;
    w.z = (vy1 && vx0) ? wy1 * (1.f - lx) : 0.f;
    w.w = (vy1 && vx1) ? wy1 * lx         : 0.f;

    const int y0c = min(max(y0, 0), H_ - 1), y1c = min(max(y1, 0), H_ - 1);
    const int x0c = min(max(x0, 0), W_ - 1), x1c = min(max(x1, 0), W_ - 1);

    int4 o;
    if (NHWC) {
      const int gb = g * CG_;
      o.x = (y0c * W_ + x0c) * C_ + gb;
      o.y = (y0c * W_ + x1c) * C_ + gb;
      o.z = (y1c * W_ + x0c) * C_ + gb;
      o.w = (y1c * W_ + x1c) * C_ + gb;
    } else {
      o.x = y0c * W_ + x0c;
      o.y = y0c * W_ + x1c;
      o.z = y1c * W_ + x0c;
      o.w = y1c * W_ + x1c;
    }
    s_o[tid] = o;
    s_w[tid] = w;
  }
  __syncthreads();

  // ---- phase 2: per-thread 4-channel accumulation over 9 taps ----
  const int ci = tid & 15;   // channel quad within group: channels ci*4 .. ci*4+3
  const int wi = tid >> 4;   // pixel within chunk: 0..15

  float4 acc = make_float4(0.f, 0.f, 0.f, 0.f);

  if (NHWC) {
    const float* xb = x + (size_t)b * (HW_ * C_) + g * CG_ + ci * 4;
#pragma unroll
    for (int k = 0; k < 9; ++k) {
      const int e = wi * 9 + k;
      const int4   o = s_o[e];   // already includes g*CG_ via gb
      const float4 w = s_w[e];
      // NOTE: o already contains g*CG_; xb also added it -> subtract once here
      const float4 v00 = *(const float4*)(xb + (o.x - g * CG_));
      const float4 v01 = *(const float4*)(xb + (o.y - g * CG_));
      const float4 v10 = *(const float4*)(xb + (o.z - g * CG_));
      const float4 v11 = *(const float4*)(xb + (o.w - g * CG_));
      acc.x += w.x * v00.x + w.y * v01.x + w.z * v10.x + w.w * v11.x;
      acc.y += w.x * v00.y + w.y * v01.y + w.z * v10.y + w.w * v11.y;
      acc.z += w.x * v00.z + w.y * v01.z + w.z * v10.z + w.w * v11.z;
      acc.w += w.x * v00.w + w.y * v01.w + w.z * v10.w + w.w * v11.w;
    }
  } else {
    const float* xb = x + (size_t)(b * C_ + g * CG_ + ci * 4) * HW_;
    float a0 = 0.f, a1 = 0.f, a2 = 0.f, a3 = 0.f;
#pragma unroll
    for (int k = 0; k < 9; ++k) {
      const int e = wi * 9 + k;
      const int4   o = s_o[e];
      const float4 w = s_w[e];
      const float* x0p = xb;
      const float* x1p = xb + HW_;
      const float* x2p = xb + 2 * HW_;
      const float* x3p = xb + 3 * HW_;
      a0 += w.x * x0p[o.x] + w.y * x0p[o.y] + w.z * x0p[o.z] + w.w * x0p[o.w];
      a1 += w.x * x1p[o.x] + w.y * x1p[o.y] + w.z * x1p[o.z] + w.w * x1p[o.w];
      a2 += w.x * x2p[o.x] + w.y * x2p[o.y] + w.z * x2p[o.z] + w.w * x2p[o.w];
      a3 += w.x * x3p[o.x] + w.y * x3p[o.y] + w.z * x3p[o.z] + w.w * x3p[o.w];
    }
    acc = make_float4(a0, a1, a2, a3);
  }

  // ---- stage to LDS: [channel][wo] with stride 17 (2-way conflicts = free) ----
  s_out[(ci * 4 + 0) * 17 + wi] = acc.x;
  s_out[(ci * 4 + 1) * 17 + wi] = acc.y;
  s_out[(ci * 4 + 2) * 17 + wi] = acc.z;
  s_out[(ci * 4 + 3) * 17 + wi] = acc.w;
  __syncthreads();

  // ---- coalesced store: lanes along wo (16 x 4B = 64B segments) ----
  float* obp = out + ((size_t)(b * C_ + g * CG_) * H_ + ho) * W_ + woq * 16;
  const int wlane = tid & 15;
  const int crow  = tid >> 4;  // 0..15
#pragma unroll
  for (int q = 0; q < 4; ++q) {
    const int c = crow + q * 16;
    obp[(size_t)c * HW_ + wlane] = s_out[c * 17 + wlane];
  }
}

// ---------------------------------------------------------------------------
extern "C" void kernel_launch(void* const* d_in, const int* in_sizes, int n_in,
                              void* d_out, int out_size, void* d_ws, size_t ws_size,
                              hipStream_t stream) {
  const float* inp = (const float*)d_in[0];
  const float* off = (const float*)d_in[1];
  const float* msk = (const float*)d_in[2];
  float* out = (float*)d_out;

  const size_t need = (size_t)B_ * C_ * HW_ * sizeof(float);  // 33.5 MB
  if (ws_size >= need) {
    float* xt = (float*)d_ws;
    dim3 gt(HW_ / 32, C_ / 32, B_);  // (128, 8, 8)
    nchw_to_nhwc<<<gt, dim3(32, 8), 0, stream>>>(inp, xt);
    deform_main<true><<<dim3(4, H_, B_ * G_), 256, 0, stream>>>(xt, off, msk, out);
  } else {
    deform_main<false><<<dim3(4, H_, B_ * G_), 256, 0, stream>>>(inp, off, msk, out);
  }
}

// Round 2
// 42.576 us; speedup vs baseline: 1.4782x; 1.4782x over previous
//
#include <hip/hip_runtime.h>
#include <hip/hip_fp16.h>

#define B_  8
#define C_  256
#define H_  64
#define W_  64
#define G_  4
#define CG_ 64
#define K_  9
#define HW_ (H_ * W_)  // 4096

// ---------------------------------------------------------------------------
// Kernel 1: NCHW fp32 -> NHWC fp16 ([B,C,HW] -> [B,HW,C]), 64ch x 64px tiles.
// LDS holds packed half2 (channel pairs) so writes are 4B/lane, 128B/wave-16.
// ---------------------------------------------------------------------------
__global__ __launch_bounds__(256) void to_nhwc_f16(const float* __restrict__ in,
                                                   __half* __restrict__ out) {
  __shared__ unsigned int tile[32][65];  // [channel-pair][pixel]
  const int b  = blockIdx.z;
  const int p0 = blockIdx.x * 64;
  const int c0 = blockIdx.y * 64;
  const int tid = threadIdx.x;
  const float* src = in + (size_t)b * C_ * HW_;
  __half* dst = out + (size_t)b * HW_ * C_;

  const int px = tid & 63;       // pixel within tile
  const int cp0 = tid >> 6;      // 4 channel-pair rows per pass
#pragma unroll
  for (int i = 0; i < 8; ++i) {
    const int cp = cp0 + i * 4;            // 0..31
    const int c = c0 + cp * 2;
    const float v0 = src[(size_t)c * HW_ + p0 + px];
    const float v1 = src[(size_t)(c + 1) * HW_ + p0 + px];
    const unsigned int lo = (unsigned int)__half_as_ushort(__float2half(v0));
    const unsigned int hi = (unsigned int)__half_as_ushort(__float2half(v1));
    tile[cp][px] = lo | (hi << 16);
  }
  __syncthreads();

  const int cpair = tid & 31;    // lanes along channel pairs: 32 x 4B = 128B
  const int pr0   = tid >> 5;    // 8 pixel rows per pass
#pragma unroll
  for (int i = 0; i < 8; ++i) {
    const int p = pr0 + i * 8;
    *(unsigned int*)(dst + (size_t)(p0 + p) * C_ + c0 + 2 * cpair) = tile[cpair][p];
  }
}

// ---------------------------------------------------------------------------
// Kernel 2: deformable sampling from NHWC fp16.
//   block = (b, g, ho, wo-half): 256 threads = 8 channel-octets x 32 wo.
//   phase 1: 288 (pixel,tap) param sets -> LDS (corner offsets + weights)
//   phase 2: each thread: 8 channels, 9 taps, 4 corners; 16B half8 gathers;
//            fp32 accumulate (v_fma_mix); stage 64ch x 32wo in LDS; store
//            coalesced 128B segments to NCHW fp32 output.
// ---------------------------------------------------------------------------
__global__ __launch_bounds__(256) void deform_f16(const __half* __restrict__ x,
                                                  const float* __restrict__ off,
                                                  const float* __restrict__ msk,
                                                  float* __restrict__ out) {
  __shared__ int4   s_o[288];
  __shared__ float4 s_w[288];
  __shared__ float  s_out[CG_ * 33];

  const int wo0 = blockIdx.x * 32;
  const int ho  = blockIdx.y;
  const int b   = blockIdx.z >> 2;
  const int g   = blockIdx.z & 3;
  const int tid = threadIdx.x;

  // ---- phase 1: sampling params for 32 pixels x 9 taps ----
  for (int e = tid; e < 288; e += 256) {
    const int wi = e / 9, k = e - wi * 9;
    const int wo = wo0 + wi;
    const int ky = k / 3, kx = k - ky * 3;
    const int och = (g * K_ + k) * 2;
    const size_t ob = ((size_t)(b * (2 * G_ * K_) + och) * H_ + ho) * W_ + wo;
    const float dy = off[ob];
    const float dx = off[ob + HW_];
    const float m  = msk[((size_t)(b * (G_ * K_) + g * K_ + k) * H_ + ho) * W_ + wo];

    const float py = (float)(ho - 1 + ky) + dy;
    const float px = (float)(wo - 1 + kx) + dx;
    const float fy = floorf(py), fx = floorf(px);
    const int y0 = (int)fy, x0 = (int)fx;
    const int y1 = y0 + 1,  x1 = x0 + 1;
    const float ly = py - fy, lx = px - fx;

    const bool vy0 = ((unsigned)y0 < (unsigned)H_), vy1 = ((unsigned)y1 < (unsigned)H_);
    const bool vx0 = ((unsigned)x0 < (unsigned)W_), vx1 = ((unsigned)x1 < (unsigned)W_);
    const float wy0 = (1.f - ly) * m, wy1 = ly * m;

    float4 w;
    w.x = (vy0 && vx0) ? wy0 * (1.f - lx) : 0.f;
    w.y = (vy0 && vx1) ? wy0 * lx         : 0.f;
    w.z = (vy1 && vx0) ? wy1 * (1.f - lx) : 0.f;
    w.w = (vy1 && vx1) ? wy1 * lx         : 0.f;

    const int y0c = min(max(y0, 0), H_ - 1), y1c = min(max(y1, 0), H_ - 1);
    const int x0c = min(max(x0, 0), W_ - 1), x1c = min(max(x1, 0), W_ - 1);

    const int gb = g * CG_;
    int4 o;  // element offsets into NHWC fp16, incl. group base
    o.x = (y0c * W_ + x0c) * C_ + gb;
    o.y = (y0c * W_ + x1c) * C_ + gb;
    o.z = (y1c * W_ + x0c) * C_ + gb;
    o.w = (y1c * W_ + x1c) * C_ + gb;
    s_o[e] = o;
    s_w[e] = w;
  }
  __syncthreads();

  // ---- phase 2 ----
  const int ci = tid & 7;   // channel octet: channels ci*8..ci*8+7
  const int wi = tid >> 3;  // 0..31
  const __half* xb = x + (size_t)b * (HW_ * C_) + ci * 8;

  float acc[8] = {0.f, 0.f, 0.f, 0.f, 0.f, 0.f, 0.f, 0.f};

#pragma unroll
  for (int k = 0; k < 9; ++k) {
    const int e = wi * 9 + k;
    const int4   o = s_o[e];
    const float4 w = s_w[e];
    const float4 r00 = *(const float4*)(xb + o.x);
    const float4 r01 = *(const float4*)(xb + o.y);
    const float4 r10 = *(const float4*)(xb + o.z);
    const float4 r11 = *(const float4*)(xb + o.w);
    const __half* h00 = (const __half*)&r00;
    const __half* h01 = (const __half*)&r01;
    const __half* h10 = (const __half*)&r10;
    const __half* h11 = (const __half*)&r11;
#pragma unroll
    for (int j = 0; j < 8; ++j) {
      float a = acc[j];
      a = fmaf(w.x, __half2float(h00[j]), a);
      a = fmaf(w.y, __half2float(h01[j]), a);
      a = fmaf(w.z, __half2float(h10[j]), a);
      a = fmaf(w.w, __half2float(h11[j]), a);
      acc[j] = a;
    }
  }

  // ---- stage to LDS [channel][wo], stride 33 ----
#pragma unroll
  for (int j = 0; j < 8; ++j) s_out[(ci * 8 + j) * 33 + wi] = acc[j];
  __syncthreads();

  // ---- coalesced store: 32 lanes x 4B = 128B segments ----
  float* ob = out + ((size_t)(b * C_ + g * CG_)) * HW_ + ho * W_ + wo0;
  const int wlane = tid & 31;
  const int cr    = tid >> 5;  // 0..7
#pragma unroll
  for (int q = 0; q < 8; ++q) {
    const int c = cr + q * 8;
    ob[(size_t)c * HW_ + wlane] = s_out[c * 33 + wlane];
  }
}

// ---------------------------------------------------------------------------
// Fallback (no workspace): fp32 NCHW gathers, 4 ch/thread (round-1 kernel).
// ---------------------------------------------------------------------------
__global__ __launch_bounds__(256) void deform_f32_nchw(const float* __restrict__ x,
                                                       const float* __restrict__ off,
                                                       const float* __restrict__ msk,
                                                       float* __restrict__ out) {
  __shared__ int4   s_o[144];
  __shared__ float4 s_w[144];
  const int woq = blockIdx.x;
  const int ho  = blockIdx.y;
  const int b   = blockIdx.z >> 2;
  const int g   = blockIdx.z & 3;
  const int tid = threadIdx.x;

  if (tid < 144) {
    const int wi = tid / 9, k = tid - wi * 9;
    const int wo = woq * 16 + wi;
    const int ky = k / 3, kx = k - ky * 3;
    const int och = (g * K_ + k) * 2;
    const size_t ob = ((size_t)(b * (2 * G_ * K_) + och) * H_ + ho) * W_ + wo;
    const float dy = off[ob];
    const float dx = off[ob + HW_];
    const float m  = msk[((size_t)(b * (G_ * K_) + g * K_ + k) * H_ + ho) * W_ + wo];
    const float py = (float)(ho - 1 + ky) + dy;
    const float px = (float)(wo - 1 + kx) + dx;
    const float fy = floorf(py), fx = floorf(px);
    const int y0 = (int)fy, x0 = (int)fx;
    const int y1 = y0 + 1,  x1 = x0 + 1;
    const float ly = py - fy, lx = px - fx;
    const bool vy0 = ((unsigned)y0 < (unsigned)H_), vy1 = ((unsigned)y1 < (unsigned)H_);
    const bool vx0 = ((unsigned)x0 < (unsigned)W_), vx1 = ((unsigned)x1 < (unsigned)W_);
    const float wy0 = (1.f - ly) * m, wy1 = ly * m;
    float4 w;
    w.x = (vy0 && vx0) ? wy0 * (1.f - lx) : 0.f;
    w.y = (vy0 && vx1) ? wy0 * lx         : 0.f;
    w.z = (vy1 && vx0) ? wy1 * (1.f - lx) : 0.f;
    w.w = (vy1 && vx1) ? wy1 * lx         : 0.f;
    const int y0c = min(max(y0, 0), H_ - 1), y1c = min(max(y1, 0), H_ - 1);
    const int x0c = min(max(x0, 0), W_ - 1), x1c = min(max(x1, 0), W_ - 1);
    s_o[tid] = make_int4(y0c * W_ + x0c, y0c * W_ + x1c, y1c * W_ + x0c, y1c * W_ + x1c);
    s_w[tid] = w;
  }
  __syncthreads();

  const int ci = tid & 15, wi = tid >> 4;
  const float* xb = x + (size_t)(b * C_ + g * CG_ + ci * 4) * HW_;
  float a0 = 0.f, a1 = 0.f, a2 = 0.f, a3 = 0.f;
#pragma unroll
  for (int k = 0; k < 9; ++k) {
    const int e = wi * 9 + k;
    const int4   o = s_o[e];
    const float4 w = s_w[e];
    a0 += w.x * xb[o.x] + w.y * xb[o.y] + w.z * xb[o.z] + w.w * xb[o.w];
    const float* x1p = xb + HW_;
    a1 += w.x * x1p[o.x] + w.y * x1p[o.y] + w.z * x1p[o.z] + w.w * x1p[o.w];
    const float* x2p = xb + 2 * HW_;
    a2 += w.x * x2p[o.x] + w.y * x2p[o.y] + w.z * x2p[o.z] + w.w * x2p[o.w];
    const float* x3p = xb + 3 * HW_;
    a3 += w.x * x3p[o.x] + w.y * x3p[o.y] + w.z * x3p[o.z] + w.w * x3p[o.w];
  }
  float* ob = out + ((size_t)(b * C_ + g * CG_ + ci * 4)) * HW_ + ho * W_ + woq * 16 + wi;
  ob[0] = a0; ob[HW_] = a1; ob[2 * HW_] = a2; ob[3 * HW_] = a3;
}

// ---------------------------------------------------------------------------
extern "C" void kernel_launch(void* const* d_in, const int* in_sizes, int n_in,
                              void* d_out, int out_size, void* d_ws, size_t ws_size,
                              hipStream_t stream) {
  const float* inp = (const float*)d_in[0];
  const float* off = (const float*)d_in[1];
  const float* msk = (const float*)d_in[2];
  float* out = (float*)d_out;

  const size_t need = (size_t)B_ * C_ * HW_ * sizeof(__half);  // 16.8 MB
  if (ws_size >= need) {
    __half* xt = (__half*)d_ws;
    to_nhwc_f16<<<dim3(HW_ / 64, C_ / 64, B_), 256, 0, stream>>>(inp, xt);
    deform_f16<<<dim3(2, H_, B_ * G_), 256, 0, stream>>>(xt, off, msk, out);
  } else {
    deform_f32_nchw<<<dim3(4, H_, B_ * G_), 256, 0, stream>>>(inp, off, msk, out);
  }
}